// Round 14
// baseline (135.523 us; speedup 1.0000x reference)
//
#include <hip/hip_runtime.h>
#include <hip/hip_bf16.h>

// ---------------------------------------------------------------------------
// RnnGruModel: MLP (1600->60->15->10) fused with GRU-layer0 input-gate
// precompute, then 3 stacked GRU layers (H=5) + output projection.
// R14: ONE fused kernel. Block = 1 batch (128 blocks x 640 thr):
//   wave 0   = GRU consumer (R9-exact systolic gate-per-lane scan)
//   waves 1-8= MLP producers: MFMA X@W1^T for a 32-timestep chunk of THIS
//              batch (rows t*128+b), each wave = (K-quarter, M-frag) of the
//              verified R13 split-K tile; partials -> LDS (stride-68 pad).
//   wave 9   = tail: reduce 4 K-partials + tanh/W2/W3/wih0 -> gi ring (gbuf)
// 2-deep pipeline, ONE __syncthreads per iteration, 10 iterations:
//   producers(chunk i) || tail(chunk i-1) || consumer(chunk i-2).
// MLP time (~45us standalone) hides under the latency-bound GRU scan.
// Layouts: X (T,B,F) row-major, row r = t*128 + b.  Output (T,1,B): t*128+b.
// ---------------------------------------------------------------------------

#define T_DIM 256
#define B_DIM 128
#define F_DIM 1600
#define H1_DIM 60
#define H2_DIM 15
#define H3_DIM 10
#define GH 5
#define NSTEP 50          // MLP K-steps of 32 (1600/32)
#define CT 32             // chunk: timesteps per buffer
#define NCH (T_DIM / CT)  // 8 chunks
#define PBSTR 68          // partial-tile row stride (floats): pad vs bank hits
#define NPW 8             // producer waves

#define DPP_SHR5  0x115   // row_shr:5  (lane i <- lane i-5 within 16-lane row)
#define DPP_SHR10 0x11A   // row_shr:10 (lane i <- lane i-10)

typedef __attribute__((ext_vector_type(8))) short bf16x8;   // MFMA A/B frag (4 VGPRs)
typedef __attribute__((ext_vector_type(4))) float f32x4;    // MFMA C/D frag

__device__ __forceinline__ float fast_tanh(float x) {
    float e = __expf(2.0f * x);
    return 1.0f - __fdividef(2.0f, e + 1.0f);   // safe at +-inf
}
__device__ __forceinline__ float fast_sigmoid(float x) {
    return __fdividef(1.0f, 1.0f + __expf(-x)); // safe at +-inf
}
__device__ __forceinline__ ushort f2bf_rn(float x) {        // round-to-nearest bf16
    uint u = __float_as_uint(x);
    u += 0x7fffu + ((u >> 16) & 1u);
    return (ushort)(u >> 16);
}
template <int CTRL>
__device__ __forceinline__ float dppf(float v) {
    return __int_as_float(
        __builtin_amdgcn_mov_dpp(__float_as_int(v), CTRL, 0xf, 0xf, true));
}
__device__ __forceinline__ float bperm(int addr, float v) {
    return __int_as_float(__builtin_amdgcn_ds_bpermute(addr, __float_as_int(v)));
}

// ---------------------------------------------------------------------------
// Kernel 0: pack W1 (60x1600 fp32, zero-padded to 64 rows) into frag-ordered
// bf16 hi/lo pairs (unchanged, verified).
// ---------------------------------------------------------------------------
__global__ __launch_bounds__(256) void pack_w1_kernel(
    const float* __restrict__ W1, ushort* __restrict__ Wp)
{
    const int s  = blockIdx.x;       // 0..49
    const int t  = threadIdx.x;
    const int nf = t >> 6;
    const int l  = t & 63;
    const int n  = nf * 16 + (l & 15);
    const int g  = l >> 4;

    ushort hi[8], lo[8];
#pragma unroll
    for (int j = 0; j < 8; ++j) {
        const int k = s * 32 + g * 8 + j;
        const float v = (n < H1_DIM) ? W1[n * F_DIM + k] : 0.0f;
        const ushort h = f2bf_rn(v);
        const float hf = __uint_as_float(((uint)h) << 16);
        const float r  = v - hf;                       // exact
        hi[j] = h;
        lo[j] = (ushort)(__float_as_uint(r) >> 16);    // truncate: |err| ~ 2^-17 |v|
    }
    ushort* dst = Wp + ((size_t)(s * 8 + nf * 2)) * 512 + l * 8;
#pragma unroll
    for (int j = 0; j < 8; ++j) dst[j] = hi[j];
#pragma unroll
    for (int j = 0; j < 8; ++j) dst[512 + j] = lo[j];
}

// ---------------------------------------------------------------------------
// consumer helpers (R9-exact)
// ---------------------------------------------------------------------------
#define PREF(CB, TL) do { pre = lptr[(CB) * (CT * 16) + (TL) * 16]; } while (0)

#define GSTEP(S, PREFCODE) do {                                             \
    /* dots: aA = bA(+gi) + wi.x ; aB = bB + wh.h  (ref-exact order) */     \
    float aA = bA + pre;                                                    \
    _Pragma("unroll") for (int _j = 0; _j < GH; ++_j)                       \
        aA = fmaf(wi[_j], xn[_j], aA);                                      \
    float aB = fmaf(wh[0], hn[0], bB);                                      \
    _Pragma("unroll") for (int _j = 1; _j < GH; ++_j)                       \
        aB = fmaf(wh[_j], hn[_j], aB);                                      \
    PREFCODE                                                                \
    const float sAv = aA + aB;                                              \
    const float sg  = fast_sigmoid(sAv);                                    \
    const float rn  = dppf<DPP_SHR10>(sg);   /* r_i -> n-lane (g-10) */     \
    const float zn  = dppf<DPP_SHR5>(sg);    /* z_i -> n-lane (g-5)  */     \
    if (lane == 48 && (unsigned)((S) - 3) < (unsigned)T_DIM)                \
        out[((S) - 3) * B_DIM + b] = sAv;    /* projection pre-activation */\
    const float nv = fast_tanh(fmaf(rn, aB, aA));                           \
    const float hu = fmaf(zn, hm - nv, nv);                                 \
    const bool _valid = (unsigned)((S) - row) < (unsigned)T_DIM;            \
    hm = _valid ? hu : hm;                                                  \
    /* replicate h (own row) and x (prev row) for next step */              \
    _Pragma("unroll") for (int _j = 0; _j < GH; ++_j) {                     \
        hn[_j] = bperm(a_self[_j], hm);                                     \
        xn[_j] = bperm(a_prev[_j], hm);                                     \
    }                                                                       \
} while (0)

// ---------------------------------------------------------------------------
// Kernel 1: fused MLP + GRU. Grid: 128 blocks x 640 threads (10 waves).
// ---------------------------------------------------------------------------
__global__ __launch_bounds__(640, 1) void fused_kernel(
    const float* __restrict__ X,
    const ushort* __restrict__ Wp,
    const float* __restrict__ b1,
    const float* __restrict__ W2, const float* __restrict__ b2,
    const float* __restrict__ W3, const float* __restrict__ b3,
    const float* __restrict__ wih0, const float* __restrict__ bih0,
    const float* __restrict__ whh0, const float* __restrict__ bhh0,
    const float* __restrict__ wih1, const float* __restrict__ whh1,
    const float* __restrict__ bih1, const float* __restrict__ bhh1,
    const float* __restrict__ wih2, const float* __restrict__ whh2,
    const float* __restrict__ bih2, const float* __restrict__ bhh2,
    const float* __restrict__ Wout, const float* __restrict__ bout,
    float* __restrict__ out)
{
    __shared__ float PB[2][4][2][16 * PBSTR];  // 69.6 KB: [buf][kq][mf] partials
    __shared__ float gbuf[2][CT][16];          // 4 KB gi ring

    const int tid  = threadIdx.x;
    const int wv   = __builtin_amdgcn_readfirstlane(tid >> 6);
    const int lane = tid & 63;
    const int b    = blockIdx.x;               // one batch per block

    if (wv == 0) {
        // ================= GRU consumer (R9-exact) =========================
        const int row = lane >> 4;             // 0..2 = layer, 3 = projection
        const int g   = lane & 15;             // gate (r:0-4, z:5-9, n:10-14)

        float wi[GH], wh[GH];
        float bA = 0.f, bB = 0.f;
#pragma unroll
        for (int j = 0; j < GH; ++j) { wi[j] = 0.f; wh[j] = 0.f; }

        if (row == 0) {
            if (g < 15) {                      // L0: x-side is in gi (incl. bih0)
#pragma unroll
                for (int j = 0; j < GH; ++j) wh[j] = whh0[g * GH + j];
                bB = bhh0[g];
            }
        } else if (row < 3) {
            const float* wip = (row == 1) ? wih1 : wih2;
            const float* whp = (row == 1) ? whh1 : whh2;
            const float* bip = (row == 1) ? bih1 : bih2;
            const float* bhp = (row == 1) ? bhh1 : bhh2;
            if (g < 15) {
#pragma unroll
                for (int j = 0; j < GH; ++j) {
                    wi[j] = wip[g * GH + j];
                    wh[j] = whp[g * GH + j];
                }
                bA = bip[g];
                bB = bhp[g];
            }
        } else if (g == 0) {                   // projection: y = Wout.h2 + bout
#pragma unroll
            for (int j = 0; j < GH; ++j) wi[j] = Wout[j];
            bA = bout[0];
        }

        int a_self[GH], a_prev[GH];
        const int sbase = row * 16;
        const int pbase = ((row + 3) & 3) * 16;    // row-1 mod 4 (row0 wraps; x*0)
#pragma unroll
        for (int j = 0; j < GH; ++j) {
            a_self[j] = (sbase + 10 + j) << 2;
            a_prev[j] = (pbase + 10 + j) << 2;
        }

        const float* lptr = &gbuf[0][0][(row == 0) ? g : 15];

        float hn[GH] = {0.f, 0.f, 0.f, 0.f, 0.f};
        float xn[GH] = {0.f, 0.f, 0.f, 0.f, 0.f};
        float hm = 0.f, pre = 0.f;

        for (int i = 0; i < NCH + 2; ++i) {
            if (i >= 2) {
                const int cc = i - 2;
                const int cb = cc & 1;
                PREF(cb, 0);                   // gbuf[cb] published 1 sync ago
#pragma unroll 2
                for (int tl = 0; tl < CT; ++tl) {
                    const int s = cc * CT + tl;
                    GSTEP(s, if (tl + 1 < CT) { PREF(cb, tl + 1); });
                }
            }
            __syncthreads();
        }
        // drain: 3 wall steps flush the layer pipeline (pre stale, h masked)
        for (int s = T_DIM; s < T_DIM + 3; ++s) {
            GSTEP(s, ;);
        }
        return;
    }

    if (wv <= NPW) {
        // ================= MLP producers (R13 MFMA transplant) =============
        const int q  = (wv - 1) & 3;           // K-quarter
        const int mf = (wv - 1) >> 2;          // M-frag (16 timesteps)
        const int lm = lane & 15;              // A-row / B-col lane index
        const int g  = lane >> 4;              // k-slot group
        const int s0 = (q * NSTEP) >> 2;       // 0,12,25,37
        const int s1 = ((q + 1) * NSTEP) >> 2; // 12,25,37,50

        for (int i = 0; i < NCH + 2; ++i) {
            if (i < NCH) {
                // A rows: timesteps t = i*32 + mf*16 + lm of batch b
                const float* ap = X
                    + (size_t)((i * CT + mf * 16 + lm) * B_DIM + b) * F_DIM
                    + s0 * 32 + g * 8;

                f32x4 acc[4];
#pragma unroll
                for (int nf = 0; nf < 4; ++nf)
                    acc[nf] = (f32x4){0.f, 0.f, 0.f, 0.f};

                float4 x0 = *(const float4*)(ap);
                float4 x1 = *(const float4*)(ap + 4);

                for (int s = s0; s < s1; ++s) {
                    float4 n0 = make_float4(0.f, 0.f, 0.f, 0.f);
                    float4 n1 = n0;
                    if (s + 1 < s1) {
                        n0 = *(const float4*)(ap + (s + 1 - s0) * 32);
                        n1 = *(const float4*)(ap + (s + 1 - s0) * 32 + 4);
                    }
                    bf16x8 bh[4], bl[4];
                    const ushort* wp_s = Wp + (size_t)s * 4096 + lane * 8;
#pragma unroll
                    for (int nf = 0; nf < 4; ++nf) {
                        bh[nf] = *(const bf16x8*)(wp_s + (nf * 2 + 0) * 512);
                        bl[nf] = *(const bf16x8*)(wp_s + (nf * 2 + 1) * 512);
                    }
                    const float xs8[8] = {x0.x, x0.y, x0.z, x0.w,
                                          x1.x, x1.y, x1.z, x1.w};
                    bf16x8 ah, al;
#pragma unroll
                    for (int j = 0; j < 8; ++j) {
                        const float v = xs8[j];
                        const uint  u = __float_as_uint(v);
                        const uint uh = (u + 0x7fffu + ((u >> 16) & 1u)) & 0xffff0000u;
                        const float hf = __uint_as_float(uh);
                        const float r  = v - hf;               // exact
                        ah[j] = (short)(uh >> 16);
                        al[j] = (short)(__float_as_uint(r) >> 16);
                    }
#pragma unroll
                    for (int nf = 0; nf < 4; ++nf) {
                        f32x4 c = acc[nf];
                        c = __builtin_amdgcn_mfma_f32_16x16x32_bf16(al, bh[nf], c, 0, 0, 0);
                        c = __builtin_amdgcn_mfma_f32_16x16x32_bf16(ah, bl[nf], c, 0, 0, 0);
                        c = __builtin_amdgcn_mfma_f32_16x16x32_bf16(ah, bh[nf], c, 0, 0, 0);
                        acc[nf] = c;
                    }
                    x0 = n0; x1 = n1;
                }

                // partials -> LDS (C/D map: col=lane&15, row=g*4+qq), pad 68
                float* myred = &PB[i & 1][q][mf][0];
#pragma unroll
                for (int nf = 0; nf < 4; ++nf)
#pragma unroll
                    for (int qq = 0; qq < 4; ++qq)
                        myred[(g * 4 + qq) * PBSTR + nf * 16 + lm] = acc[nf][qq];
            }
            __syncthreads();
        }
        return;
    }

    // ================= tail wave (R13 tail transplant) =====================
    for (int i = 0; i < NCH + 2; ++i) {
        if (i >= 1 && i <= NCH && lane < 32) {
            const int cc = i - 1;              // chunk whose gi we produce
            const int cb = cc & 1;
            const int mf = lane >> 4, rr = lane & 15;

            // reduce 4 K-quarter partials (float4, stride-68 rows)
            float s60[H1_DIM];
            const float4* p0 = (const float4*)&PB[cb][0][mf][rr * PBSTR];
            const float4* p1 = (const float4*)&PB[cb][1][mf][rr * PBSTR];
            const float4* p2 = (const float4*)&PB[cb][2][mf][rr * PBSTR];
            const float4* p3 = (const float4*)&PB[cb][3][mf][rr * PBSTR];
#pragma unroll
            for (int o4 = 0; o4 < 15; ++o4) {
                const float4 a = p0[o4], bq = p1[o4], cq = p2[o4], dq = p3[o4];
                s60[o4 * 4 + 0] = (a.x + bq.x) + (cq.x + dq.x);
                s60[o4 * 4 + 1] = (a.y + bq.y) + (cq.y + dq.y);
                s60[o4 * 4 + 2] = (a.z + bq.z) + (cq.z + dq.z);
                s60[o4 * 4 + 3] = (a.w + bq.w) + (cq.w + dq.w);
            }

            float h1v[H1_DIM];
#pragma unroll
            for (int o = 0; o < H1_DIM; ++o)
                h1v[o] = fast_tanh(s60[o] + b1[o]);

            float h2v[H2_DIM];
#pragma unroll
            for (int j = 0; j < H2_DIM; ++j) {
                float sacc = b2[j];
#pragma unroll
                for (int o = 0; o < H1_DIM; ++o) sacc += W2[j * H1_DIM + o] * h1v[o];
                h2v[j] = fast_tanh(sacc);
            }

            float h3v[H3_DIM];
#pragma unroll
            for (int m = 0; m < H3_DIM; ++m) {
                float sacc = b3[m];
#pragma unroll
                for (int j = 0; j < H2_DIM; ++j) sacc += W3[m * H2_DIM + j] * h2v[j];
                h3v[m] = sacc;
            }

            float gv[15];
#pragma unroll
            for (int qy = 0; qy < 15; ++qy) {
                float sacc = bih0[qy];
#pragma unroll
                for (int m = 0; m < H3_DIM; ++m) sacc += wih0[qy * H3_DIM + m] * h3v[m];
                gv[qy] = sacc;
            }

            float4* dst = (float4*)&gbuf[cb][lane][0];   // timestep-in-chunk = lane
            dst[0] = make_float4(gv[0],  gv[1],  gv[2],  gv[3]);
            dst[1] = make_float4(gv[4],  gv[5],  gv[6],  gv[7]);
            dst[2] = make_float4(gv[8],  gv[9],  gv[10], gv[11]);
            dst[3] = make_float4(gv[12], gv[13], gv[14], 0.0f);
        }
        __syncthreads();
    }
}

// ---------------------------------------------------------------------------
extern "C" void kernel_launch(void* const* d_in, const int* in_sizes, int n_in,
                              void* d_out, int out_size, void* d_ws, size_t ws_size,
                              hipStream_t stream)
{
    (void)in_sizes; (void)n_in; (void)out_size; (void)ws_size;

    const float* X    = (const float*)d_in[0];
    const float* W1   = (const float*)d_in[1];
    const float* b1   = (const float*)d_in[2];
    const float* W2   = (const float*)d_in[3];
    const float* b2   = (const float*)d_in[4];
    const float* W3   = (const float*)d_in[5];
    const float* b3   = (const float*)d_in[6];
    const float* wih0 = (const float*)d_in[7];
    const float* whh0 = (const float*)d_in[8];
    const float* bih0 = (const float*)d_in[9];
    const float* bhh0 = (const float*)d_in[10];
    const float* wih1 = (const float*)d_in[11];
    const float* whh1 = (const float*)d_in[12];
    const float* bih1 = (const float*)d_in[13];
    const float* bhh1 = (const float*)d_in[14];
    const float* wih2 = (const float*)d_in[15];
    const float* whh2 = (const float*)d_in[16];
    const float* bih2 = (const float*)d_in[17];
    const float* bhh2 = (const float*)d_in[18];
    const float* Wout = (const float*)d_in[19];
    const float* bout = (const float*)d_in[20];

    ushort* Wp = (ushort*)d_ws;                        // 400 frags * 1 KB = 400 KB

    pack_w1_kernel<<<NSTEP, 256, 0, stream>>>(W1, Wp);
    fused_kernel<<<B_DIM, 640, 0, stream>>>(X, Wp, b1, W2, b2, W3, b3,
                                            wih0, bih0, whh0, bhh0,
                                            wih1, whh1, bih1, bhh1,
                                            wih2, whh2, bih2, bhh2,
                                            Wout, bout, (float*)d_out);
}

// Round 15
// 133.436 us; speedup vs baseline: 1.0156x; 1.0156x over previous
//
#include <hip/hip_runtime.h>
#include <hip/hip_bf16.h>

// ---------------------------------------------------------------------------
// RnnGruModel: MLP (1600->60->15->10) fused with GRU-layer0 input-gate
// precompute, then 3 stacked GRU layers (H=5) + output projection.
// R15: fused kernel (R14 skeleton, verified absmax 0.0) with producer
// X-prefetch depth 4 (was 2). R14 was paced by the X stream at ~1.6 TB/s
// because in-flight bytes (2 MB) sat at the BW*latency knee (2.4 MB);
// depth-4 ring = 8 MB in flight -> HBM-saturating producers -> GRU-paced.
//   wave 0   = GRU consumer (R9-exact systolic gate-per-lane scan)
//   waves 1-8= MLP producers (R13 MFMA transplant + depth-4 pipeline)
//   wave 9   = tail: reduce partials + MLP tail -> gi ring
// 2-deep pipeline, ONE __syncthreads per iteration:
//   producers(chunk i) || tail(chunk i-1) || consumer(chunk i-2).
// Layouts: X (T,B,F) row-major, row r = t*128 + b.  Output (T,1,B): t*128+b.
// ---------------------------------------------------------------------------

#define T_DIM 256
#define B_DIM 128
#define F_DIM 1600
#define H1_DIM 60
#define H2_DIM 15
#define H3_DIM 10
#define GH 5
#define NSTEP 50          // MLP K-steps of 32 (1600/32)
#define CT 32             // chunk: timesteps per buffer
#define NCH (T_DIM / CT)  // 8 chunks
#define PBSTR 68          // partial-tile row stride (floats): pad vs bank hits
#define NPW 8             // producer waves

#define DPP_SHR5  0x115   // row_shr:5  (lane i <- lane i-5 within 16-lane row)
#define DPP_SHR10 0x11A   // row_shr:10 (lane i <- lane i-10)

typedef __attribute__((ext_vector_type(8))) short bf16x8;   // MFMA A/B frag (4 VGPRs)
typedef __attribute__((ext_vector_type(4))) float f32x4;    // MFMA C/D frag

__device__ __forceinline__ float fast_tanh(float x) {
    float e = __expf(2.0f * x);
    return 1.0f - __fdividef(2.0f, e + 1.0f);   // safe at +-inf
}
__device__ __forceinline__ float fast_sigmoid(float x) {
    return __fdividef(1.0f, 1.0f + __expf(-x)); // safe at +-inf
}
__device__ __forceinline__ ushort f2bf_rn(float x) {        // round-to-nearest bf16
    uint u = __float_as_uint(x);
    u += 0x7fffu + ((u >> 16) & 1u);
    return (ushort)(u >> 16);
}
template <int CTRL>
__device__ __forceinline__ float dppf(float v) {
    return __int_as_float(
        __builtin_amdgcn_mov_dpp(__float_as_int(v), CTRL, 0xf, 0xf, true));
}
__device__ __forceinline__ float bperm(int addr, float v) {
    return __int_as_float(__builtin_amdgcn_ds_bpermute(addr, __float_as_int(v)));
}

// ---------------------------------------------------------------------------
// Kernel 0: pack W1 (60x1600 fp32, zero-padded to 64 rows) into frag-ordered
// bf16 hi/lo pairs (unchanged, verified).
// ---------------------------------------------------------------------------
__global__ __launch_bounds__(256) void pack_w1_kernel(
    const float* __restrict__ W1, ushort* __restrict__ Wp)
{
    const int s  = blockIdx.x;       // 0..49
    const int t  = threadIdx.x;
    const int nf = t >> 6;
    const int l  = t & 63;
    const int n  = nf * 16 + (l & 15);
    const int g  = l >> 4;

    ushort hi[8], lo[8];
#pragma unroll
    for (int j = 0; j < 8; ++j) {
        const int k = s * 32 + g * 8 + j;
        const float v = (n < H1_DIM) ? W1[n * F_DIM + k] : 0.0f;
        const ushort h = f2bf_rn(v);
        const float hf = __uint_as_float(((uint)h) << 16);
        const float r  = v - hf;                       // exact
        hi[j] = h;
        lo[j] = (ushort)(__float_as_uint(r) >> 16);    // truncate: |err| ~ 2^-17 |v|
    }
    ushort* dst = Wp + ((size_t)(s * 8 + nf * 2)) * 512 + l * 8;
#pragma unroll
    for (int j = 0; j < 8; ++j) dst[j] = hi[j];
#pragma unroll
    for (int j = 0; j < 8; ++j) dst[512 + j] = lo[j];
}

// ---------------------------------------------------------------------------
// consumer helpers (R9-exact)
// ---------------------------------------------------------------------------
#define PREF(CB, TL) do { pre = lptr[(CB) * (CT * 16) + (TL) * 16]; } while (0)

#define GSTEP(S, PREFCODE) do {                                             \
    /* dots: aA = bA(+gi) + wi.x ; aB = bB + wh.h  (ref-exact order) */     \
    float aA = bA + pre;                                                    \
    _Pragma("unroll") for (int _j = 0; _j < GH; ++_j)                       \
        aA = fmaf(wi[_j], xn[_j], aA);                                      \
    float aB = fmaf(wh[0], hn[0], bB);                                      \
    _Pragma("unroll") for (int _j = 1; _j < GH; ++_j)                       \
        aB = fmaf(wh[_j], hn[_j], aB);                                      \
    PREFCODE                                                                \
    const float sAv = aA + aB;                                              \
    const float sg  = fast_sigmoid(sAv);                                    \
    const float rn  = dppf<DPP_SHR10>(sg);   /* r_i -> n-lane (g-10) */     \
    const float zn  = dppf<DPP_SHR5>(sg);    /* z_i -> n-lane (g-5)  */     \
    if (lane == 48 && (unsigned)((S) - 3) < (unsigned)T_DIM)                \
        out[((S) - 3) * B_DIM + b] = sAv;    /* projection pre-activation */\
    const float nv = fast_tanh(fmaf(rn, aB, aA));                           \
    const float hu = fmaf(zn, hm - nv, nv);                                 \
    const bool _valid = (unsigned)((S) - row) < (unsigned)T_DIM;            \
    hm = _valid ? hu : hm;                                                  \
    /* replicate h (own row) and x (prev row) for next step */              \
    _Pragma("unroll") for (int _j = 0; _j < GH; ++_j) {                     \
        hn[_j] = bperm(a_self[_j], hm);                                     \
        xn[_j] = bperm(a_prev[_j], hm);                                     \
    }                                                                       \
} while (0)

// ---------------------------------------------------------------------------
// Kernel 1: fused MLP + GRU. Grid: 128 blocks x 640 threads (10 waves).
// ---------------------------------------------------------------------------
__global__ __launch_bounds__(640, 1) void fused_kernel(
    const float* __restrict__ X,
    const ushort* __restrict__ Wp,
    const float* __restrict__ b1,
    const float* __restrict__ W2, const float* __restrict__ b2,
    const float* __restrict__ W3, const float* __restrict__ b3,
    const float* __restrict__ wih0, const float* __restrict__ bih0,
    const float* __restrict__ whh0, const float* __restrict__ bhh0,
    const float* __restrict__ wih1, const float* __restrict__ whh1,
    const float* __restrict__ bih1, const float* __restrict__ bhh1,
    const float* __restrict__ wih2, const float* __restrict__ whh2,
    const float* __restrict__ bih2, const float* __restrict__ bhh2,
    const float* __restrict__ Wout, const float* __restrict__ bout,
    float* __restrict__ out)
{
    __shared__ float PB[2][4][2][16 * PBSTR];  // 69.6 KB: [buf][kq][mf] partials
    __shared__ float gbuf[2][CT][16];          // 4 KB gi ring

    const int tid  = threadIdx.x;
    const int wv   = __builtin_amdgcn_readfirstlane(tid >> 6);
    const int lane = tid & 63;
    const int b    = blockIdx.x;               // one batch per block

    if (wv == 0) {
        // ================= GRU consumer (R9-exact) =========================
        const int row = lane >> 4;             // 0..2 = layer, 3 = projection
        const int g   = lane & 15;             // gate (r:0-4, z:5-9, n:10-14)

        float wi[GH], wh[GH];
        float bA = 0.f, bB = 0.f;
#pragma unroll
        for (int j = 0; j < GH; ++j) { wi[j] = 0.f; wh[j] = 0.f; }

        if (row == 0) {
            if (g < 15) {                      // L0: x-side is in gi (incl. bih0)
#pragma unroll
                for (int j = 0; j < GH; ++j) wh[j] = whh0[g * GH + j];
                bB = bhh0[g];
            }
        } else if (row < 3) {
            const float* wip = (row == 1) ? wih1 : wih2;
            const float* whp = (row == 1) ? whh1 : whh2;
            const float* bip = (row == 1) ? bih1 : bih2;
            const float* bhp = (row == 1) ? bhh1 : bhh2;
            if (g < 15) {
#pragma unroll
                for (int j = 0; j < GH; ++j) {
                    wi[j] = wip[g * GH + j];
                    wh[j] = whp[g * GH + j];
                }
                bA = bip[g];
                bB = bhp[g];
            }
        } else if (g == 0) {                   // projection: y = Wout.h2 + bout
#pragma unroll
            for (int j = 0; j < GH; ++j) wi[j] = Wout[j];
            bA = bout[0];
        }

        int a_self[GH], a_prev[GH];
        const int sbase = row * 16;
        const int pbase = ((row + 3) & 3) * 16;    // row-1 mod 4 (row0 wraps; x*0)
#pragma unroll
        for (int j = 0; j < GH; ++j) {
            a_self[j] = (sbase + 10 + j) << 2;
            a_prev[j] = (pbase + 10 + j) << 2;
        }

        const float* lptr = &gbuf[0][0][(row == 0) ? g : 15];

        float hn[GH] = {0.f, 0.f, 0.f, 0.f, 0.f};
        float xn[GH] = {0.f, 0.f, 0.f, 0.f, 0.f};
        float hm = 0.f, pre = 0.f;

        for (int i = 0; i < NCH + 2; ++i) {
            if (i >= 2) {
                const int cc = i - 2;
                const int cb = cc & 1;
                PREF(cb, 0);                   // gbuf[cb] published 1 sync ago
#pragma unroll 2
                for (int tl = 0; tl < CT; ++tl) {
                    const int s = cc * CT + tl;
                    GSTEP(s, if (tl + 1 < CT) { PREF(cb, tl + 1); });
                }
            }
            __syncthreads();
        }
        // drain: 3 wall steps flush the layer pipeline (pre stale, h masked)
        for (int s = T_DIM; s < T_DIM + 3; ++s) {
            GSTEP(s, ;);
        }
        return;
    }

    if (wv <= NPW) {
        // ======== MLP producers (R13 MFMA transplant, depth-4 pipeline) ====
        const int q  = (wv - 1) & 3;           // K-quarter
        const int mf = (wv - 1) >> 2;          // M-frag (16 timesteps)
        const int lm = lane & 15;              // A-row / B-col lane index
        const int g  = lane >> 4;              // k-slot group
        const int s0 = (q * NSTEP) >> 2;       // 0,12,25,37
        const int s1 = ((q + 1) * NSTEP) >> 2; // 12,25,37,50  (>= 12 steps)

        for (int i = 0; i < NCH + 2; ++i) {
            if (i < NCH) {
                // A rows: timesteps t = i*32 + mf*16 + lm of batch b
                const float* ap = X
                    + (size_t)((i * CT + mf * 16 + lm) * B_DIM + b) * F_DIM
                    + s0 * 32 + g * 8;

                f32x4 acc[4];
#pragma unroll
                for (int nf = 0; nf < 4; ++nf)
                    acc[nf] = (f32x4){0.f, 0.f, 0.f, 0.f};

                // depth-4 software pipeline on A (8 float4 in flight / lane)
                float4 p00 = *(const float4*)(ap + 0 * 32);
                float4 p01 = *(const float4*)(ap + 0 * 32 + 4);
                float4 p10 = *(const float4*)(ap + 1 * 32);
                float4 p11 = *(const float4*)(ap + 1 * 32 + 4);
                float4 p20 = *(const float4*)(ap + 2 * 32);
                float4 p21 = *(const float4*)(ap + 2 * 32 + 4);
                float4 p30 = *(const float4*)(ap + 3 * 32);
                float4 p31 = *(const float4*)(ap + 3 * 32 + 4);

                for (int s = s0; s < s1; ++s) {
                    const float4 x0 = p00, x1 = p01;
                    // rotate + issue load for s+4 (keeps 6-8 loads in flight)
                    p00 = p10; p01 = p11;
                    p10 = p20; p11 = p21;
                    p20 = p30; p21 = p31;
                    if (s + 4 < s1) {
                        p30 = *(const float4*)(ap + (s + 4 - s0) * 32);
                        p31 = *(const float4*)(ap + (s + 4 - s0) * 32 + 4);
                    }
                    // B frags: per-lane 16B loads, L2-resident
                    bf16x8 bh[4], bl[4];
                    const ushort* wp_s = Wp + (size_t)s * 4096 + lane * 8;
#pragma unroll
                    for (int nf = 0; nf < 4; ++nf) {
                        bh[nf] = *(const bf16x8*)(wp_s + (nf * 2 + 0) * 512);
                        bl[nf] = *(const bf16x8*)(wp_s + (nf * 2 + 1) * 512);
                    }
                    const float xs8[8] = {x0.x, x0.y, x0.z, x0.w,
                                          x1.x, x1.y, x1.z, x1.w};
                    bf16x8 ah, al;
#pragma unroll
                    for (int j = 0; j < 8; ++j) {
                        const float v = xs8[j];
                        const uint  u = __float_as_uint(v);
                        const uint uh = (u + 0x7fffu + ((u >> 16) & 1u)) & 0xffff0000u;
                        const float hf = __uint_as_float(uh);
                        const float r  = v - hf;               // exact
                        ah[j] = (short)(uh >> 16);
                        al[j] = (short)(__float_as_uint(r) >> 16);
                    }
#pragma unroll
                    for (int nf = 0; nf < 4; ++nf) {
                        f32x4 c = acc[nf];
                        c = __builtin_amdgcn_mfma_f32_16x16x32_bf16(al, bh[nf], c, 0, 0, 0);
                        c = __builtin_amdgcn_mfma_f32_16x16x32_bf16(ah, bl[nf], c, 0, 0, 0);
                        c = __builtin_amdgcn_mfma_f32_16x16x32_bf16(ah, bh[nf], c, 0, 0, 0);
                        acc[nf] = c;
                    }
                }

                // partials -> LDS (C/D map: col=lane&15, row=g*4+qq), pad 68
                float* myred = &PB[i & 1][q][mf][0];
#pragma unroll
                for (int nf = 0; nf < 4; ++nf)
#pragma unroll
                    for (int qq = 0; qq < 4; ++qq)
                        myred[(g * 4 + qq) * PBSTR + nf * 16 + lm] = acc[nf][qq];
            }
            __syncthreads();
        }
        return;
    }

    // ================= tail wave (R13 tail transplant) =====================
    for (int i = 0; i < NCH + 2; ++i) {
        if (i >= 1 && i <= NCH && lane < 32) {
            const int cc = i - 1;              // chunk whose gi we produce
            const int cb = cc & 1;
            const int mf = lane >> 4, rr = lane & 15;

            // reduce 4 K-quarter partials (float4, stride-68 rows)
            float s60[H1_DIM];
            const float4* p0 = (const float4*)&PB[cb][0][mf][rr * PBSTR];
            const float4* p1 = (const float4*)&PB[cb][1][mf][rr * PBSTR];
            const float4* p2 = (const float4*)&PB[cb][2][mf][rr * PBSTR];
            const float4* p3 = (const float4*)&PB[cb][3][mf][rr * PBSTR];
#pragma unroll
            for (int o4 = 0; o4 < 15; ++o4) {
                const float4 a = p0[o4], bq = p1[o4], cq = p2[o4], dq = p3[o4];
                s60[o4 * 4 + 0] = (a.x + bq.x) + (cq.x + dq.x);
                s60[o4 * 4 + 1] = (a.y + bq.y) + (cq.y + dq.y);
                s60[o4 * 4 + 2] = (a.z + bq.z) + (cq.z + dq.z);
                s60[o4 * 4 + 3] = (a.w + bq.w) + (cq.w + dq.w);
            }

            float h1v[H1_DIM];
#pragma unroll
            for (int o = 0; o < H1_DIM; ++o)
                h1v[o] = fast_tanh(s60[o] + b1[o]);

            float h2v[H2_DIM];
#pragma unroll
            for (int j = 0; j < H2_DIM; ++j) {
                float sacc = b2[j];
#pragma unroll
                for (int o = 0; o < H1_DIM; ++o) sacc += W2[j * H1_DIM + o] * h1v[o];
                h2v[j] = fast_tanh(sacc);
            }

            float h3v[H3_DIM];
#pragma unroll
            for (int m = 0; m < H3_DIM; ++m) {
                float sacc = b3[m];
#pragma unroll
                for (int j = 0; j < H2_DIM; ++j) sacc += W3[m * H2_DIM + j] * h2v[j];
                h3v[m] = sacc;
            }

            float gv[15];
#pragma unroll
            for (int qy = 0; qy < 15; ++qy) {
                float sacc = bih0[qy];
#pragma unroll
                for (int m = 0; m < H3_DIM; ++m) sacc += wih0[qy * H3_DIM + m] * h3v[m];
                gv[qy] = sacc;
            }

            float4* dst = (float4*)&gbuf[cb][lane][0];   // timestep-in-chunk = lane
            dst[0] = make_float4(gv[0],  gv[1],  gv[2],  gv[3]);
            dst[1] = make_float4(gv[4],  gv[5],  gv[6],  gv[7]);
            dst[2] = make_float4(gv[8],  gv[9],  gv[10], gv[11]);
            dst[3] = make_float4(gv[12], gv[13], gv[14], 0.0f);
        }
        __syncthreads();
    }
}

// ---------------------------------------------------------------------------
extern "C" void kernel_launch(void* const* d_in, const int* in_sizes, int n_in,
                              void* d_out, int out_size, void* d_ws, size_t ws_size,
                              hipStream_t stream)
{
    (void)in_sizes; (void)n_in; (void)out_size; (void)ws_size;

    const float* X    = (const float*)d_in[0];
    const float* W1   = (const float*)d_in[1];
    const float* b1   = (const float*)d_in[2];
    const float* W2   = (const float*)d_in[3];
    const float* b2   = (const float*)d_in[4];
    const float* W3   = (const float*)d_in[5];
    const float* b3   = (const float*)d_in[6];
    const float* wih0 = (const float*)d_in[7];
    const float* whh0 = (const float*)d_in[8];
    const float* bih0 = (const float*)d_in[9];
    const float* bhh0 = (const float*)d_in[10];
    const float* wih1 = (const float*)d_in[11];
    const float* whh1 = (const float*)d_in[12];
    const float* bih1 = (const float*)d_in[13];
    const float* bhh1 = (const float*)d_in[14];
    const float* wih2 = (const float*)d_in[15];
    const float* whh2 = (const float*)d_in[16];
    const float* bih2 = (const float*)d_in[17];
    const float* bhh2 = (const float*)d_in[18];
    const float* Wout = (const float*)d_in[19];
    const float* bout = (const float*)d_in[20];

    ushort* Wp = (ushort*)d_ws;                        // 400 frags * 1 KB = 400 KB

    pack_w1_kernel<<<NSTEP, 256, 0, stream>>>(W1, Wp);
    fused_kernel<<<B_DIM, 640, 0, stream>>>(X, Wp, b1, W2, b2, W3, b3,
                                            wih0, bih0, whh0, bhh0,
                                            wih1, whh1, bih1, bhh1,
                                            wih2, whh2, bih2, bhh2,
                                            Wout, bout, (float*)d_out);
}